// Round 12
// baseline (160.620 us; speedup 1.0000x reference)
//
#include <hip/hip_runtime.h>
#include <hip/hip_bf16.h>
#include <stdint.h>

using bf16 = __hip_bfloat16;
typedef __bf16 bf16x8 __attribute__((ext_vector_type(8)));
typedef float f32x4 __attribute__((ext_vector_type(4)));
typedef unsigned short u16x8 __attribute__((ext_vector_type(8)));
typedef unsigned short u16x4 __attribute__((ext_vector_type(4)));

#define AS1 __attribute__((address_space(1)))
#define AS3 __attribute__((address_space(3)))

__device__ inline unsigned short f2b(float f) {
    union { __hip_bfloat16 h; unsigned short u; } cv;
    cv.h = __float2bfloat16(f);
    return cv.u;
}

// ---------------- fused fp32 -> bf16 converts (one dispatch) ----------------
__global__ __launch_bounds__(256) void cvt6(
    const float* __restrict__ i0, const float* __restrict__ i1,
    const float* __restrict__ i2, const float* __restrict__ i3,
    const float* __restrict__ i4, const float* __restrict__ i5,
    u16x8* __restrict__ o0, u16x8* __restrict__ o1,
    u16x8* __restrict__ o2, u16x8* __restrict__ o3,
    u16x8* __restrict__ o4, u16x8* __restrict__ o5,
    long nbig, long nsmall)
{
    const int y = blockIdx.y;
    const float* in = y == 0 ? i0 : (y == 1 ? i1 : (y == 2 ? i2 : (y == 3 ? i3 : (y == 4 ? i4 : i5))));
    u16x8* out = y == 0 ? o0 : (y == 1 ? o1 : (y == 2 ? o2 : (y == 3 ? o3 : (y == 4 ? o4 : o5))));
    const long n8 = (y < 2) ? nbig : nsmall;
    long i = (long)blockIdx.x * blockDim.x + threadIdx.x;
    const long stride = (long)gridDim.x * blockDim.x;
    const float4* in4 = (const float4*)in;
    for (; i < n8; i += stride) {
        float4 x = in4[2 * i], z = in4[2 * i + 1];
        u16x8 o;
        o[0] = f2b(x.x); o[1] = f2b(x.y); o[2] = f2b(x.z); o[3] = f2b(x.w);
        o[4] = f2b(z.x); o[5] = f2b(z.y); o[6] = f2b(z.z); o[7] = f2b(z.w);
        out[i] = o;
    }
}

template <typename T> __device__ inline void storev(T* p, float v);
template <> __device__ inline void storev<float>(float* p, float v) { *p = v; }
template <> __device__ inline void storev<bf16>(bf16* p, float v) { *p = __float2bfloat16(v); }

// ================= tiled GEMM: C = A(MxK) * B^T(NxK), BN=256 =================
// 256x256 tile, 8 waves 2Mx4N, 8-phase one-barrier schedule (r11 structure).
// MODE 0: fused K|V projections   MODE 1: fused Q | V'=V@Wp^T (seg1 -> V'T)
template <typename OutT, int MODE>
__global__ __launch_bounds__(512, 2) void gemmX(
    const bf16* __restrict__ A0, const bf16* __restrict__ A1,
    const bf16* __restrict__ B0p, const bf16* __restrict__ B1p,
    OutT* __restrict__ C0, OutT* __restrict__ C1,
    const float* __restrict__ bias0, const float* __restrict__ bias1,
    float scale, int lda, int ldb, int ldc, int Kdim,
    long sA, long sB, long sC)
{
    __shared__ __align__(16) char lds[131072];

    const int nwg = gridDim.x;
    const int bid = blockIdx.x;
    const int s = (nwg & 7) ? bid : ((bid & 7) * (nwg >> 3) + (bid >> 3));

    int bm, ccol0, rowB0, seg = 0;
    const bf16 *A, *B;
    OutT* C;
    const float* bias = nullptr;

    if constexpr (MODE == 0) {                 // K|V: 256 = 32bm x 8bn
        bm = s >> 3; const int bnl = s & 7; seg = bnl >> 2;
        A = A0; B = B0p; rowB0 = bnl * 256;
        C = seg ? C1 : C0; bias = seg ? bias1 : bias0;
        ccol0 = (bnl & 3) * 256;
    } else {                                   // Q | VWp: 256 = 2seg x 32bm x 4bn
        seg = s >> 7; const int r = s & 127; bm = r >> 2; const int bn = r & 3;
        A = seg ? A1 : A0; B = seg ? B1p : B0p;
        C = seg ? C1 : C0; bias = seg ? nullptr : bias0;
        rowB0 = bn * 256; ccol0 = bn * 256;
    }

    const int KT = Kdim >> 6;
    const int NIT = KT >> 1;

    const int tid = threadIdx.x;
    const int lane = tid & 63;
    const int w = tid >> 6;
    const int wm = w >> 2;
    const int wn = w & 3;

    const int rowA0 = bm * 256;

    const int rr  = tid >> 3;
    const int lch = (tid & 7) ^ (rr & 7);
    const bf16* gAt = A + (long)(rowA0 + rr) * lda + lch * 8;
    const bf16* gBt = B + (long)(rowB0 + rr) * ldb + lch * 8;

#define LA(b) (lds + (b) * 65536)
#define LB(b) (lds + 32768 + (b) * 65536)

    auto SG2 = [&](const bf16* g, int ld, char* dst) {
        __builtin_amdgcn_global_load_lds((const AS1 void*)g,
            (AS3 void*)(dst + tid * 16), 16, 0, 0);
        __builtin_amdgcn_global_load_lds((const AS1 void*)(g + (long)64 * ld),
            (AS3 void*)(dst + 8192 + tid * 16), 16, 0, 0);
    };
    auto ST_A = [&](int kt, int half, int b) {
        SG2(gAt + (long)kt * 64 + (long)half * 128 * lda, lda, LA(b) + half * 16384);
    };
    auto ST_B = [&](int kt, int half, int b) {
        SG2(gBt + (long)kt * 64 + (long)half * 128 * ldb, ldb, LB(b) + half * 16384);
    };

    const int abase = (wm * 128 + (lane & 15)) * 128;
    const int bbase = (wn * 64 + (lane & 15)) * 128;
    const int cc0 = (((lane >> 4) << 4)) ^ ((lane & 7) << 4);
    const int cc1 = cc0 ^ 64;

#define RAF(b, mh, mi, kk) (*(const bf16x8*)(LA(b) + abase + (mh)*8192 + (mi)*2048 + ((kk) ? cc1 : cc0)))
#define RBF(b, ni, kk)     (*(const bf16x8*)(LB(b) + bbase + (ni)*2048 + ((kk) ? cc1 : cc0)))

    f32x4 acc[8][4] = {};
    bf16x8 ar[4][2], blo[2][2], bhi[2][2];

#define RD_A2(b, mh, MI0) { ar[MI0][0] = RAF(b, mh, MI0, 0); ar[MI0][1] = RAF(b, mh, MI0, 1); \
                            ar[(MI0)+1][0] = RAF(b, mh, (MI0)+1, 0); ar[(MI0)+1][1] = RAF(b, mh, (MI0)+1, 1); }
#define RD_BLO(b)   { blo[0][0] = RBF(b, 0, 0); blo[0][1] = RBF(b, 0, 1); blo[1][0] = RBF(b, 1, 0); blo[1][1] = RBF(b, 1, 1); }
#define RD_BHI(b)   { bhi[0][0] = RBF(b, 2, 0); bhi[0][1] = RBF(b, 2, 1); bhi[1][0] = RBF(b, 3, 0); bhi[1][1] = RBF(b, 3, 1); }

#define MQ1(MI, bb, MH, NB) { \
    f32x4 t0_ = acc[(MH)*4 + (MI)][(NB)]; \
    t0_ = __builtin_amdgcn_mfma_f32_16x16x32_bf16(ar[MI][0], bb[0][0], t0_, 0, 0, 0); \
    t0_ = __builtin_amdgcn_mfma_f32_16x16x32_bf16(ar[MI][1], bb[0][1], t0_, 0, 0, 0); \
    acc[(MH)*4 + (MI)][(NB)] = t0_; \
    f32x4 t1_ = acc[(MH)*4 + (MI)][(NB) + 1]; \
    t1_ = __builtin_amdgcn_mfma_f32_16x16x32_bf16(ar[MI][0], bb[1][0], t1_, 0, 0, 0); \
    t1_ = __builtin_amdgcn_mfma_f32_16x16x32_bf16(ar[MI][1], bb[1][1], t1_, 0, 0, 0); \
    acc[(MH)*4 + (MI)][(NB) + 1] = t1_; }

#define SCHEDB __builtin_amdgcn_sched_barrier(0)
#define BSYNC { SCHEDB; __builtin_amdgcn_s_barrier(); SCHEDB; }

    auto PRIO1 = [&]() { __builtin_amdgcn_s_setprio(1); };
    auto PRIO0 = [&]() { __builtin_amdgcn_s_setprio(0); };

    ST_A(0, 0, 0); ST_A(0, 1, 0); ST_B(0, 0, 0); ST_B(0, 1, 0);
    ST_B(1, 0, 1); ST_B(1, 1, 1);
    asm volatile("s_waitcnt vmcnt(4)" ::: "memory");
    BSYNC;
    RD_BLO(0); RD_A2(0, 0, 0); RD_A2(0, 0, 2);

    for (int i = 0; i < NIT; ++i) {
        const int t0 = 2 * i;
        const bool last = (i == NIT - 1);

        ST_A(t0 + 1, 0, 1);
        BSYNC; PRIO1();
        RD_BHI(0);
        MQ1(0, blo, 0, 0); MQ1(1, blo, 0, 0); MQ1(2, blo, 0, 0); MQ1(3, blo, 0, 0);
        PRIO0();

        ST_A(t0 + 1, 1, 1);
        BSYNC; PRIO1();
        MQ1(0, bhi, 0, 2); MQ1(1, bhi, 0, 2); MQ1(2, bhi, 0, 2); MQ1(3, bhi, 0, 2);
        RD_A2(0, 1, 0); RD_A2(0, 1, 2);
        PRIO0();

        BSYNC; PRIO1();
        MQ1(0, bhi, 1, 2); MQ1(1, bhi, 1, 2); MQ1(2, bhi, 1, 2); MQ1(3, bhi, 1, 2);
        PRIO0();

        if (!last) { ST_B(t0 + 2, 0, 0); ST_B(t0 + 2, 1, 0);
                     asm volatile("s_waitcnt vmcnt(4)" ::: "memory"); }
        else       { asm volatile("s_waitcnt vmcnt(0)" ::: "memory"); }
        BSYNC; PRIO1();
        MQ1(0, blo, 1, 0); MQ1(1, blo, 1, 0); MQ1(2, blo, 1, 0); MQ1(3, blo, 1, 0);
        RD_BLO(1); RD_A2(1, 0, 0); RD_A2(1, 0, 2);
        PRIO0();

        if (!last) ST_A(t0 + 2, 0, 0);
        BSYNC; PRIO1();
        RD_BHI(1);
        MQ1(0, blo, 0, 0); MQ1(1, blo, 0, 0); MQ1(2, blo, 0, 0); MQ1(3, blo, 0, 0);
        PRIO0();

        if (!last) ST_A(t0 + 2, 1, 0);
        BSYNC; PRIO1();
        MQ1(0, bhi, 0, 2); MQ1(1, bhi, 0, 2); MQ1(2, bhi, 0, 2); MQ1(3, bhi, 0, 2);
        RD_A2(1, 1, 0); RD_A2(1, 1, 2);
        PRIO0();

        BSYNC; PRIO1();
        MQ1(0, bhi, 1, 2); MQ1(1, bhi, 1, 2); MQ1(2, bhi, 1, 2); MQ1(3, bhi, 1, 2);
        PRIO0();

        if (!last) { ST_B(t0 + 3, 0, 1); ST_B(t0 + 3, 1, 1);
                     asm volatile("s_waitcnt vmcnt(4)" ::: "memory"); }
        BSYNC; PRIO1();
        MQ1(0, blo, 1, 0); MQ1(1, blo, 1, 0); MQ1(2, blo, 1, 0); MQ1(3, blo, 1, 0);
        if (!last) { RD_BLO(0); RD_A2(0, 0, 0); RD_A2(0, 0, 2); }
        PRIO0();
    }

    // ==================== epilogues ====================
    char* tw = lds + w * 16384;
    if (MODE == 1 && seg == 1) {
        // V'T per batch via per-wave LDS transpose; 16B/lane column stores.
#pragma unroll
        for (int ni = 0; ni < 4; ++ni) {
            const int cl = ni * 16 + (lane & 15);
            const int sw = 8 * (cl & 7);
#pragma unroll
            for (int mi = 0; mi < 8; ++mi) {
                const int rlb = mi * 16 + ((lane >> 4) << 2);
                u16x4 o;
                o[0] = f2b(acc[mi][ni][0]); o[1] = f2b(acc[mi][ni][1]);
                o[2] = f2b(acc[mi][ni][2]); o[3] = f2b(acc[mi][ni][3]);
                *(u16x4*)(tw + cl * 256 + 2 * (rlb ^ sw)) = o;
            }
        }
        asm volatile("s_waitcnt lgkmcnt(0)" ::: "memory");
        __builtin_amdgcn_sched_barrier(0);
        const int m0 = rowA0 + wm * 128;
        const int z2 = m0 >> 11, mr = m0 & 2047;
        bf16* CT = (bf16*)C + (long)z2 * 2097152 + (long)(ccol0 + wn * 64 + lane) * 2048 + mr;
        const char* tr = tw + lane * 256;
        const int sw2 = lane & 7;
#pragma unroll
        for (int rb = 0; rb < 16; ++rb) {
            u16x8 v = *(const u16x8*)(tr + 16 * (rb ^ sw2));
            *(u16x8*)(CT + 8 * rb) = v;
        }
    } else {
        // bf16 row-retile: full 16B/lane row-segment stores
        const int q = lane >> 4, t = lane & 15;
        const int c0 = ccol0 + wn * 64 + t;
#pragma unroll
        for (int mi = 0; mi < 8; ++mi) {
            char* tm = tw + mi * 2048;
#pragma unroll
            for (int ni = 0; ni < 4; ++ni) {
                const float bv = bias ? bias[c0 + ni * 16] : 0.0f;
                const int cb = (t + 16 * ni) * 2;
#pragma unroll
                for (int j = 0; j < 4; ++j) {
                    const int rl = q * 4 + j;
                    *(bf16*)(tm + rl * 128 + (cb ^ ((rl & 7) << 4))) =
                        __float2bfloat16(acc[mi][ni][j] * scale + bv);
                }
            }
        }
        asm volatile("s_waitcnt lgkmcnt(0)" ::: "memory");
        __builtin_amdgcn_sched_barrier(0);
        const int rr2 = lane >> 2, chb = (lane & 3) * 2;
        const int gr0 = rowA0 + wm * 128;
        bf16* Cb = (bf16*)C;
        const int gcb = ccol0 + wn * 64;
#pragma unroll
        for (int mi = 0; mi < 8; ++mi) {
            const char* tm = tw + mi * 2048;
            const long gr = gr0 + mi * 16 + rr2;
#pragma unroll
            for (int k = 0; k < 2; ++k) {
                const int chunk = chb + k;
                u16x8 v = *(const u16x8*)(tm + rr2 * 128 + ((chunk << 4) ^ ((rr2 & 7) << 4)));
                *(u16x8*)(Cb + gr * (long)ldc + gcb + chunk * 8) = v;
            }
        }
    }
#undef RAF
#undef RBF
#undef RD_A2
#undef RD_BLO
#undef RD_BHI
#undef MQ1
#undef LA
#undef LB
}

// ========== causal scores at 256x128 tiles (288 blocks, packed grid) ==========
// P' = exp((Q @ K^T)*scale) masked; row partial sums -> part[(z*8+bm)*32 + bn*2+wn].
// 8 waves 4Mx2N (per-wave 64x64), r5-proven 4-phase double-buffered pipeline.
__global__ __launch_bounds__(512, 2) void score128(
    const bf16* __restrict__ Qp, const bf16* __restrict__ Kp,
    bf16* __restrict__ SP, float* __restrict__ part, float scale)
{
    __shared__ __align__(16) char lds[98304];   // 2 x (A 32KB + B 16KB)

    const int bid = blockIdx.x;
    const int s = (bid & 7) * 36 + (bid >> 3);   // 288 % 8 == 0
    const int z = s / 72, f = s % 72;
    int bm = 0;
    while ((bm + 1) * (bm + 2) <= f) ++bm;       // bm(bm+1) <= f
    const int bn = f - bm * (bm + 1);            // bn in [0, 2bm+2)

    const bf16* A = Qp + (long)z * 2048 * 1024;
    const bf16* B = Kp + (long)z * 2048 * 1024;
    bf16* C = SP + (long)z * 2048 * 2048;
    const int rowA0 = bm * 256, rowB0 = bn * 128;

    const int tid = threadIdx.x;
    const int lane = tid & 63;
    const int w = tid >> 6;
    const int wm = w >> 1, wn = w & 1;           // 4M x 2N

    const int rr  = tid >> 3;
    const int lch = (tid & 7) ^ (rr & 7);
    const bf16* gAt = A + (long)(rowA0 + rr) * 1024 + lch * 8;
    const bf16* gBt = B + (long)(rowB0 + rr) * 1024 + lch * 8;

#define LA(b) (lds + (b) * 49152)
#define LB(b) (lds + 32768 + (b) * 49152)

    auto SG2 = [&](const bf16* g, char* dst) {
        __builtin_amdgcn_global_load_lds((const AS1 void*)g,
            (AS3 void*)(dst + tid * 16), 16, 0, 0);
        __builtin_amdgcn_global_load_lds((const AS1 void*)(g + (long)64 * 1024),
            (AS3 void*)(dst + 8192 + tid * 16), 16, 0, 0);
    };
    auto ST_A = [&](int kt, int half, int b) {
        SG2(gAt + (long)kt * 64 + (long)half * 128 * 1024, LA(b) + half * 16384);
    };
    auto ST_B1 = [&](int kt, int b) {
        SG2(gBt + (long)kt * 64, LB(b));
    };

    const int abase = (wm * 64 + (lane & 15)) * 128;
    const int bbase = (wn * 64 + (lane & 15)) * 128;
    const int cc0 = (((lane >> 4) << 4)) ^ ((lane & 7) << 4);
    const int cc1 = cc0 ^ 64;

#define RAF(b, mi, kk) (*(const bf16x8*)(LA(b) + abase + (mi)*2048 + ((kk) ? cc1 : cc0)))
#define RBF(b, ni, kk) (*(const bf16x8*)(LB(b) + bbase + (ni)*2048 + ((kk) ? cc1 : cc0)))

    f32x4 acc[4][4] = {};
    bf16x8 ar[4][2], blo[2][2], bhi[2][2];

#define RD_A2(b, MI0) { ar[MI0][0] = RAF(b, MI0, 0); ar[MI0][1] = RAF(b, MI0, 1); \
                        ar[(MI0)+1][0] = RAF(b, (MI0)+1, 0); ar[(MI0)+1][1] = RAF(b, (MI0)+1, 1); }
#define RD_BLO(b)   { blo[0][0] = RBF(b, 0, 0); blo[0][1] = RBF(b, 0, 1); blo[1][0] = RBF(b, 1, 0); blo[1][1] = RBF(b, 1, 1); }
#define RD_BHI(b)   { bhi[0][0] = RBF(b, 2, 0); bhi[0][1] = RBF(b, 2, 1); bhi[1][0] = RBF(b, 3, 0); bhi[1][1] = RBF(b, 3, 1); }

#define MQ1(MI, bb, NB) { \
    f32x4 t0_ = acc[MI][(NB)]; \
    t0_ = __builtin_amdgcn_mfma_f32_16x16x32_bf16(ar[MI][0], bb[0][0], t0_, 0, 0, 0); \
    t0_ = __builtin_amdgcn_mfma_f32_16x16x32_bf16(ar[MI][1], bb[0][1], t0_, 0, 0, 0); \
    acc[MI][(NB)] = t0_; \
    f32x4 t1_ = acc[MI][(NB) + 1]; \
    t1_ = __builtin_amdgcn_mfma_f32_16x16x32_bf16(ar[MI][0], bb[1][0], t1_, 0, 0, 0); \
    t1_ = __builtin_amdgcn_mfma_f32_16x16x32_bf16(ar[MI][1], bb[1][1], t1_, 0, 0, 0); \
    acc[MI][(NB) + 1] = t1_; }

#define SCHEDB __builtin_amdgcn_sched_barrier(0)
#define WAIT_LGKM0 { asm volatile("s_waitcnt lgkmcnt(0)" ::: "memory"); SCHEDB; }
#define WAIT_LGKM4 { asm volatile("s_waitcnt lgkmcnt(4)" ::: "memory"); SCHEDB; }

    auto BAR = [&]() { __builtin_amdgcn_s_barrier(); SCHEDB; };
    auto PRIO1 = [&]() { __builtin_amdgcn_s_setprio(1); };
    auto PRIO0 = [&]() { __builtin_amdgcn_s_setprio(0); };

    // prologue: tiles 0,1 full (6 loads each); vm(6) retires tile0
    ST_A(0, 0, 0); ST_A(0, 1, 0); ST_B1(0, 0);
    ST_A(1, 0, 1); ST_A(1, 1, 1); ST_B1(1, 1);
    asm volatile("s_waitcnt vmcnt(6)" ::: "memory");
    BAR();

    const int NIT = 8;                           // KT = 16
    for (int i = 0; i < NIT; ++i) {
        const int t0 = 2 * i;
        const bool last = (i == NIT - 1);

        RD_BLO(0); RD_A2(0, 0); RD_A2(0, 2); SCHEDB; RD_BHI(0);
        BAR(); WAIT_LGKM4; PRIO1();
        MQ1(0, blo, 0); MQ1(1, blo, 0); MQ1(2, blo, 0); MQ1(3, blo, 0);
        PRIO0(); BAR();

        if (!last) { ST_A(t0 + 2, 0, 0); ST_A(t0 + 2, 1, 0);
                     asm volatile("s_waitcnt vmcnt(4)" ::: "memory"); }
        else       { asm volatile("s_waitcnt vmcnt(0)" ::: "memory"); }
        BAR(); WAIT_LGKM0; PRIO1();
        MQ1(0, bhi, 2); MQ1(1, bhi, 2); MQ1(2, bhi, 2); MQ1(3, bhi, 2);
        PRIO0(); BAR();

        RD_BLO(1); RD_A2(1, 0); RD_A2(1, 2); SCHEDB; RD_BHI(1);
        if (!last) ST_B1(t0 + 2, 0);
        BAR(); WAIT_LGKM4; PRIO1();
        MQ1(0, blo, 0); MQ1(1, blo, 0); MQ1(2, blo, 0); MQ1(3, blo, 0);
        PRIO0(); BAR();

        if (!last) { ST_A(t0 + 3, 0, 1); ST_A(t0 + 3, 1, 1); ST_B1(t0 + 3, 1);
                     asm volatile("s_waitcnt vmcnt(6)" ::: "memory"); }
        BAR(); WAIT_LGKM0; PRIO1();
        MQ1(0, bhi, 2); MQ1(1, bhi, 2); MQ1(2, bhi, 2); MQ1(3, bhi, 2);
        PRIO0(); BAR();
    }

    // ---- epilogue: masked exp + row partial sums + retiled P' store
    const int q = lane >> 4, t = lane & 15;
    const bool diag = (bn >> 1) == bm;
    const int delta = (bn - 2 * bm) * 128;       // 0 or 128 when diag
#pragma unroll
    for (int mi = 0; mi < 4; ++mi)
#pragma unroll
        for (int ni = 0; ni < 4; ++ni)
#pragma unroll
            for (int j = 0; j < 4; ++j) {
                float e = __expf(acc[mi][ni][j] * scale);
                if (diag) {
                    const int rl = wm * 64 + mi * 16 + q * 4 + j;
                    const int cl = wn * 64 + t + ni * 16;
                    if (delta + cl > rl) e = 0.f;
                }
                e = __bfloat162float(__float2bfloat16(e));
                acc[mi][ni][j] = e;
            }

    float* pp = part + ((((long)z * 8 + bm) * 32) + bn * 2 + wn) * 256;
#pragma unroll
    for (int mi = 0; mi < 4; ++mi) {
        float rs0 = acc[mi][0][0] + acc[mi][1][0] + acc[mi][2][0] + acc[mi][3][0];
        float rs1 = acc[mi][0][1] + acc[mi][1][1] + acc[mi][2][1] + acc[mi][3][1];
        float rs2 = acc[mi][0][2] + acc[mi][1][2] + acc[mi][2][2] + acc[mi][3][2];
        float rs3 = acc[mi][0][3] + acc[mi][1][3] + acc[mi][2][3] + acc[mi][3][3];
#pragma unroll
        for (int d = 1; d < 16; d <<= 1) {
            rs0 += __shfl_xor(rs0, d); rs1 += __shfl_xor(rs1, d);
            rs2 += __shfl_xor(rs2, d); rs3 += __shfl_xor(rs3, d);
        }
        if (t == mi) {
            float4 o; o.x = rs0; o.y = rs1; o.z = rs2; o.w = rs3;
            *(float4*)(pp + wm * 64 + mi * 16 + q * 4) = o;
        }
    }

    // retiled bf16 store (full 16B/lane row segments)
    char* tw = lds + w * 8192;
#pragma unroll
    for (int mi = 0; mi < 4; ++mi) {
        char* tm = tw + mi * 2048;
#pragma unroll
        for (int ni = 0; ni < 4; ++ni) {
            const int cb = (t + 16 * ni) * 2;
#pragma unroll
            for (int j = 0; j < 4; ++j) {
                const int rl = q * 4 + j;
                *(bf16*)(tm + rl * 128 + (cb ^ ((rl & 7) << 4))) =
                    __float2bfloat16(acc[mi][ni][j]);
            }
        }
    }
    asm volatile("s_waitcnt lgkmcnt(0)" ::: "memory");
    __builtin_amdgcn_sched_barrier(0);
    const int rr2 = lane >> 2, chb = (lane & 3) * 2;
    const int gr0 = rowA0 + wm * 64;
    const int gcb = rowB0 + wn * 64;
#pragma unroll
    for (int mi = 0; mi < 4; ++mi) {
        const char* tm = tw + mi * 2048;
        const long gr = gr0 + mi * 16 + rr2;
#pragma unroll
        for (int k = 0; k < 2; ++k) {
            const int chunk = chb + k;
            u16x8 v = *(const u16x8*)(tm + rr2 * 128 + ((chunk << 4) ^ ((rr2 & 7) << 4)));
            *(u16x8*)(C + gr * 2048 + gcb + chunk * 8) = v;
        }
    }
#undef RAF
#undef RBF
#undef RD_A2
#undef RD_BLO
#undef RD_BHI
#undef MQ1
#undef LA
#undef LB
}

// ============ balanced causal PV: out = (P' @ V'^T)/rowsum + bias ============
__global__ __launch_bounds__(512, 2) void pv_bal(
    const bf16* __restrict__ P, const bf16* __restrict__ VT,
    const float* __restrict__ part, float* __restrict__ out,
    const float* __restrict__ bias)
{
    __shared__ __align__(16) char lds[99328];  // 3 x 32KB bufs + 1KB inv
    float* invl = (float*)(lds + 98304);

    const int nwg = gridDim.x;
    const int bid = blockIdx.x;
    const int s = (bid & 7) * (nwg >> 3) + (bid >> 3);
    const int z = s >> 6, r = s & 63;
    const int pr = r >> 3, bn = r & 7;
    const int bmA = pr, bmB = 15 - pr;

    const bf16* Pz = P + (long)z * 2048 * 2048;
    const bf16* Vz = VT + (long)z * 1024 * 2048;

    const int tid = threadIdx.x;
    const int lane = tid & 63;
    const int w = tid >> 6;
    const int wm = w >> 2, wn = w & 3;
    const int rr = tid >> 3;
    const int lch = (tid & 7) ^ (rr & 7);

    if (tid < 256) {
        const int half = tid >> 7, rloc = tid & 127;
        const int grow = (half ? bmB : bmA) * 128 + rloc;
        const int b256 = grow >> 8, rin = grow & 255;
        const float* pp = part + (((long)z * 8 + b256) * 32) * 256 + rin;
        const int n4 = 4 * (b256 + 1);
        float s0 = 0.f, s1 = 0.f, s2 = 0.f, s3 = 0.f;
        int b4 = 0;
        for (; b4 + 4 <= n4; b4 += 4) {
            s0 += pp[(long)b4 * 256];       s1 += pp[(long)(b4 + 1) * 256];
            s2 += pp[(long)(b4 + 2) * 256]; s3 += pp[(long)(b4 + 3) * 256];
        }
        for (; b4 < n4; ++b4) s0 += pp[(long)b4 * 256];
        invl[tid] = 1.0f / ((s0 + s1) + (s2 + s3));
    }

    const bf16* gBt = Vz + (long)(bn * 128 + rr) * 2048 + lch * 8;
    const bf16* gAtA = Pz + (long)(bmA * 128 + rr) * 2048 + lch * 8;
    const bf16* gAtB = Pz + (long)(bmB * 128 + rr) * 2048 + lch * 8;

    auto SG2 = [&](const bf16* g, char* dst) {
        __builtin_amdgcn_global_load_lds((const AS1 void*)g,
            (AS3 void*)(dst + tid * 16), 16, 0, 0);
        __builtin_amdgcn_global_load_lds((const AS1 void*)(g + (long)64 * 2048),
            (AS3 void*)(dst + 8192 + tid * 16), 16, 0, 0);
    };
    auto ST = [&](const bf16* gAt, int kt, int b) {
        SG2(gAt + (long)kt * 64, lds + b * 32768);
        SG2(gBt + (long)kt * 64, lds + b * 32768 + 16384);
    };

    const int abase0 = (wm * 64 + (lane & 15)) * 128;
    const int bbase0 = 16384 + (wn * 32 + (lane & 15)) * 128;
    const int cc0 = ((lane >> 4) << 4) ^ ((lane & 7) << 4);
    const int cc1 = cc0 ^ 64;

    f32x4 acc[4][2];
    bf16x8 ar[4][2], br[2][2];

    auto RDF = [&](int t) {
        const char* base = lds + (t % 3) * 32768;
#pragma unroll
        for (int mi = 0; mi < 4; ++mi) {
            ar[mi][0] = *(const bf16x8*)(base + abase0 + mi * 2048 + cc0);
            ar[mi][1] = *(const bf16x8*)(base + abase0 + mi * 2048 + cc1);
        }
#pragma unroll
        for (int ni = 0; ni < 2; ++ni) {
            br[ni][0] = *(const bf16x8*)(base + bbase0 + ni * 2048 + cc0);
            br[ni][1] = *(const bf16x8*)(base + bbase0 + ni * 2048 + cc1);
        }
    };
    auto MFMA16 = [&]() {
#pragma unroll
        for (int mi = 0; mi < 4; ++mi)
#pragma unroll
            for (int ni = 0; ni < 2; ++ni) {
                f32x4 t_ = acc[mi][ni];
                t_ = __builtin_amdgcn_mfma_f32_16x16x32_bf16(ar[mi][0], br[ni][0], t_, 0, 0, 0);
                t_ = __builtin_amdgcn_mfma_f32_16x16x32_bf16(ar[mi][1], br[ni][1], t_, 0, 0, 0);
                acc[mi][ni] = t_;
            }
    };
    auto ZERO = [&]() {
#pragma unroll
        for (int mi = 0; mi < 4; ++mi)
#pragma unroll
            for (int ni = 0; ni < 2; ++ni) acc[mi][ni] = f32x4{0.f, 0.f, 0.f, 0.f};
    };
    auto tile_pass = [&](const bf16* gAt, int KT) {
        RDF(0);
        for (int t = 0; t < KT; ++t) {
            if (t + 2 < KT) {
                ST(gAt, t + 2, (t + 2) % 3);
                asm volatile("s_waitcnt vmcnt(4)" ::: "memory");
            } else if (t + 1 < KT) {
                asm volatile("s_waitcnt vmcnt(0)" ::: "memory");
            }
            asm volatile("s_waitcnt lgkmcnt(0)" ::: "memory");
            __builtin_amdgcn_sched_barrier(0);
            __builtin_amdgcn_s_barrier();
            __builtin_amdgcn_sched_barrier(0);
            __builtin_amdgcn_s_setprio(1);
            MFMA16();
            if (t + 1 < KT) RDF(t + 1);
            __builtin_amdgcn_s_setprio(0);
        }
    };
    auto epi = [&](int bm, int invoff) {
        const int q = lane >> 4, t16 = lane & 15;
        const int c0 = bn * 128 + wn * 32 + t16;
        float* op = out + ((long)z * 2048 + (long)bm * 128) * 1024;
#pragma unroll
        for (int mi = 0; mi < 4; ++mi)
#pragma unroll
            for (int j = 0; j < 4; ++j) {
                const int rl = wm * 64 + mi * 16 + q * 4 + j;
                const float iv = invl[invoff + rl];
#pragma unroll
                for (int ni = 0; ni < 2; ++ni) {
                    const int c = c0 + ni * 16;
                    op[(long)rl * 1024 + c] = acc[mi][ni][j] * iv + bias[c];
                }
            }
    };

    const int KTA = 2 * (bmA + 1), KTB = 2 * (bmB + 1);

    ST(gAtA, 0, 0); ST(gAtA, 1, 1);
    asm volatile("s_waitcnt vmcnt(4)" ::: "memory");
    __builtin_amdgcn_s_barrier();
    __builtin_amdgcn_sched_barrier(0);
    ZERO();
    tile_pass(gAtA, KTA);

    ST(gAtB, 0, 0); ST(gAtB, 1, 1);
    epi(bmA, 0);
    asm volatile("s_waitcnt vmcnt(0)" ::: "memory");
    __builtin_amdgcn_s_barrier();
    __builtin_amdgcn_sched_barrier(0);
    ZERO();
    tile_pass(gAtB, KTB);
    epi(bmB, 128);
}

extern "C" void kernel_launch(void* const* d_in, const int* in_sizes, int n_in,
                              void* d_out, int out_size, void* d_ws, size_t ws_size,
                              hipStream_t stream) {
    const int B = 4, S = 2048, D = 1024;
    const long MD = (long)B * S * D;
    const float scale = 0.5f / 32.0f;       // TAU / sqrt(D)

    const float* node  = (const float*)d_in[0];
    const float* label = (const float*)d_in[1];
    const float* Wq = (const float*)d_in[2];
    const float* bq = (const float*)d_in[3];
    const float* Wk = (const float*)d_in[4];
    const float* bk = (const float*)d_in[5];
    const float* Wv = (const float*)d_in[6];
    const float* bv = (const float*)d_in[7];
    const float* Wp = (const float*)d_in[8];
    const float* bp = (const float*)d_in[9];
    float* out = (float*)d_out;

    char* ws = (char*)d_ws;
    bf16* nodeb  = (bf16*)(ws);
    bf16* VTb    = nodeb;                          // alias (node dead after KV)
    bf16* labelb = (bf16*)(ws + 16777216);
    bf16* Wqb = (bf16*)(ws + 33554432);
    bf16* Wkb = (bf16*)(ws + 35651584);            // Wk|Wv contiguous
    bf16* Wvb = (bf16*)(ws + 37748736);
    bf16* Wpb = (bf16*)(ws + 39845888);
    bf16* Qb  = (bf16*)(ws + 41943040);
    bf16* Kb  = (bf16*)(ws + 58720256);
    bf16* Vb  = (bf16*)(ws + 75497472);
    float* partial = (float*)(ws + 75497472);      // alias (V dead after QVWp)
    bf16* SP  = (bf16*)(ws + 92274688);
    if (ws_size < 125829120UL) return;

    cvt6<<<dim3(512, 6), 256, 0, stream>>>(
        node, label, Wq, Wk, Wv, Wp,
        (u16x8*)nodeb, (u16x8*)labelb, (u16x8*)Wqb, (u16x8*)Wkb, (u16x8*)Wvb, (u16x8*)Wpb,
        MD / 8, (long)D * D / 8);

    // K|V projections: 256 blocks; B = stacked Wk|Wv
    gemmX<bf16, 0><<<256, 512, 0, stream>>>(
        nodeb, nullptr, Wkb, nullptr, Kb, Vb, bk, bv,
        1.0f, D, D, D, D, 0, 0, 0);

    // Q | V' = V@Wp^T (transposed write): 128+128 = 256 blocks
    gemmX<bf16, 1><<<256, 512, 0, stream>>>(
        labelb, Vb, Wqb, Wpb, Qb, VTb, bq, nullptr,
        1.0f, D, D, D, D, 0, 0, 0);

    // causal P' = exp((Q @ K^T)*scale) masked + row partial sums, packed grid
    score128<<<288, 512, 0, stream>>>(Qb, Kb, SP, partial, scale);

    // out = (P' @ V'^T) / rowsum + bp (fp32), balanced pair grid: 256 blocks
    pv_bal<<<256, 512, 0, stream>>>(SP, VTb, partial, out, bp);
}

// Round 14
// 151.524 us; speedup vs baseline: 1.0600x; 1.0600x over previous
//
#include <hip/hip_runtime.h>
#include <hip/hip_bf16.h>
#include <stdint.h>

using bf16 = __hip_bfloat16;
typedef __bf16 bf16x8 __attribute__((ext_vector_type(8)));
typedef float f32x4 __attribute__((ext_vector_type(4)));
typedef unsigned short u16x8 __attribute__((ext_vector_type(8)));
typedef unsigned short u16x4 __attribute__((ext_vector_type(4)));

#define AS1 __attribute__((address_space(1)))
#define AS3 __attribute__((address_space(3)))

__device__ inline unsigned short f2b(float f) {
    union { __hip_bfloat16 h; unsigned short u; } cv;
    cv.h = __float2bfloat16(f);
    return cv.u;
}

// ---------------- fused fp32 -> bf16 converts (one dispatch) ----------------
__global__ __launch_bounds__(256) void cvt6(
    const float* __restrict__ i0, const float* __restrict__ i1,
    const float* __restrict__ i2, const float* __restrict__ i3,
    const float* __restrict__ i4, const float* __restrict__ i5,
    u16x8* __restrict__ o0, u16x8* __restrict__ o1,
    u16x8* __restrict__ o2, u16x8* __restrict__ o3,
    u16x8* __restrict__ o4, u16x8* __restrict__ o5,
    long nbig, long nsmall)
{
    const int y = blockIdx.y;
    const float* in = y == 0 ? i0 : (y == 1 ? i1 : (y == 2 ? i2 : (y == 3 ? i3 : (y == 4 ? i4 : i5))));
    u16x8* out = y == 0 ? o0 : (y == 1 ? o1 : (y == 2 ? o2 : (y == 3 ? o3 : (y == 4 ? o4 : o5))));
    const long n8 = (y < 2) ? nbig : nsmall;
    long i = (long)blockIdx.x * blockDim.x + threadIdx.x;
    const long stride = (long)gridDim.x * blockDim.x;
    const float4* in4 = (const float4*)in;
    for (; i < n8; i += stride) {
        float4 x = in4[2 * i], z = in4[2 * i + 1];
        u16x8 o;
        o[0] = f2b(x.x); o[1] = f2b(x.y); o[2] = f2b(x.z); o[3] = f2b(x.w);
        o[4] = f2b(z.x); o[5] = f2b(z.y); o[6] = f2b(z.z); o[7] = f2b(z.w);
        out[i] = o;
    }
}

template <typename T> __device__ inline void storev(T* p, float v);
template <> __device__ inline void storev<float>(float* p, float v) { *p = v; }
template <> __device__ inline void storev<bf16>(bf16* p, float v) { *p = __float2bfloat16(v); }

// ================= tiled GEMM: C = A(MxK) * B^T(NxK), BN=256 =================
// 256x256 tile, 8 waves 2Mx4N, 8-phase one-barrier schedule with NO lgkm
// drains: ds_reads stay outstanding across barriers; compiler inserts counted
// lgkmcnt at consuming MFMAs. Stage plan (verified legal for this fragment
// layout — A/B reads interleave staging halves, so A(t2) stages only at
// P5/P6, B(t2) only at P4, B(t3) at P8, A(t1)h* at P1/P2):
//   P1:A(t1)h0->b1  P2:A(t1)h1->b1  P4:B(t2)h0+h1->b0 + vm4
//   P5:A(t2)h0->b0  P6:A(t2)h1->b0  P8:B(t3)h0+h1->b1 + vm4
// MODE 0: fused K|V projections   MODE 1: fused Q | V'=V@Wp^T (seg1 -> V'T)
// MODE 2: causal scores -> P' = exp(s*scale) masked, + row partial sums (C1)
template <typename OutT, int MODE>
__global__ __launch_bounds__(512, 2) void gemmX(
    const bf16* __restrict__ A0, const bf16* __restrict__ A1,
    const bf16* __restrict__ B0p, const bf16* __restrict__ B1p,
    OutT* __restrict__ C0, OutT* __restrict__ C1,
    const float* __restrict__ bias0, const float* __restrict__ bias1,
    float scale, int lda, int ldb, int ldc, int Kdim,
    long sA, long sB, long sC)
{
    __shared__ __align__(16) char lds[131072];

    const int nwg = gridDim.x;
    const int bid = blockIdx.x;
    const int s = (nwg & 7) ? bid : ((bid & 7) * (nwg >> 3) + (bid >> 3));

    int bm, ccol0, rowB0, seg = 0, bn_s = 0, zidx = 0;
    const bf16 *A, *B;
    OutT* C;
    const float* bias = nullptr;

    if constexpr (MODE == 0) {                 // K|V: 256 = 32bm x 8bn
        bm = s >> 3; const int bnl = s & 7; seg = bnl >> 2;
        A = A0; B = B0p; rowB0 = bnl * 256;
        C = seg ? C1 : C0; bias = seg ? bias1 : bias0;
        ccol0 = (bnl & 3) * 256;
    } else if constexpr (MODE == 1) {          // Q | VWp: 256 = 2seg x 32bm x 4bn
        seg = s >> 7; const int r = s & 127; bm = r >> 2; const int bn = r & 3;
        A = seg ? A1 : A0; B = seg ? B1p : B0p;
        C = seg ? C1 : C0; bias = seg ? nullptr : bias0;
        rowB0 = bn * 256; ccol0 = bn * 256;
    } else {                                   // scores: 144 = 4z x 36tri
        const int z = s / 36, f = s % 36;
        int m = 0;
        while ((m + 1) * (m + 2) / 2 <= f) ++m;
        bm = m; const int bn = f - m * (m + 1) / 2;
        bn_s = bn; zidx = z;
        A = A0 + (long)z * sA; B = B0p + (long)z * sB; C = C0 + (long)z * sC;
        rowB0 = bn * 256; ccol0 = bn * 256;
    }

    const int KT = Kdim >> 6;
    const int NIT = KT >> 1;

    const int tid = threadIdx.x;
    const int lane = tid & 63;
    const int w = tid >> 6;
    const int wm = w >> 2;
    const int wn = w & 3;

    const int rowA0 = bm * 256;

    const int rr  = tid >> 3;
    const int lch = (tid & 7) ^ (rr & 7);
    const bf16* gAt = A + (long)(rowA0 + rr) * lda + lch * 8;
    const bf16* gBt = B + (long)(rowB0 + rr) * ldb + lch * 8;

#define LA(b) (lds + (b) * 65536)
#define LB(b) (lds + 32768 + (b) * 65536)

    auto SG2 = [&](const bf16* g, int ld, char* dst) {
        __builtin_amdgcn_global_load_lds((const AS1 void*)g,
            (AS3 void*)(dst + tid * 16), 16, 0, 0);
        __builtin_amdgcn_global_load_lds((const AS1 void*)(g + (long)64 * ld),
            (AS3 void*)(dst + 8192 + tid * 16), 16, 0, 0);
    };
    auto ST_A = [&](int kt, int half, int b) {
        SG2(gAt + (long)kt * 64 + (long)half * 128 * lda, lda, LA(b) + half * 16384);
    };
    auto ST_B = [&](int kt, int half, int b) {
        SG2(gBt + (long)kt * 64 + (long)half * 128 * ldb, ldb, LB(b) + half * 16384);
    };

    const int abase = (wm * 128 + (lane & 15)) * 128;
    const int bbase = (wn * 64 + (lane & 15)) * 128;
    const int cc0 = (((lane >> 4) << 4)) ^ ((lane & 7) << 4);
    const int cc1 = cc0 ^ 64;

#define RAF(b, mh, mi, kk) (*(const bf16x8*)(LA(b) + abase + (mh)*8192 + (mi)*2048 + ((kk) ? cc1 : cc0)))
#define RBF(b, ni, kk)     (*(const bf16x8*)(LB(b) + bbase + (ni)*2048 + ((kk) ? cc1 : cc0)))

    f32x4 acc[8][4] = {};
    bf16x8 ar[4][2], blo[2][2], bhi[2][2];

#define RD_A2(b, mh, MI0) { ar[MI0][0] = RAF(b, mh, MI0, 0); ar[MI0][1] = RAF(b, mh, MI0, 1); \
                            ar[(MI0)+1][0] = RAF(b, mh, (MI0)+1, 0); ar[(MI0)+1][1] = RAF(b, mh, (MI0)+1, 1); }
#define RD_BLO(b)   { blo[0][0] = RBF(b, 0, 0); blo[0][1] = RBF(b, 0, 1); blo[1][0] = RBF(b, 1, 0); blo[1][1] = RBF(b, 1, 1); }
#define RD_BHI(b)   { bhi[0][0] = RBF(b, 2, 0); bhi[0][1] = RBF(b, 2, 1); bhi[1][0] = RBF(b, 3, 0); bhi[1][1] = RBF(b, 3, 1); }

#define MQ1(MI, bb, MH, NB) { \
    f32x4 t0_ = acc[(MH)*4 + (MI)][(NB)]; \
    t0_ = __builtin_amdgcn_mfma_f32_16x16x32_bf16(ar[MI][0], bb[0][0], t0_, 0, 0, 0); \
    t0_ = __builtin_amdgcn_mfma_f32_16x16x32_bf16(ar[MI][1], bb[0][1], t0_, 0, 0, 0); \
    acc[(MH)*4 + (MI)][(NB)] = t0_; \
    f32x4 t1_ = acc[(MH)*4 + (MI)][(NB) + 1]; \
    t1_ = __builtin_amdgcn_mfma_f32_16x16x32_bf16(ar[MI][0], bb[1][0], t1_, 0, 0, 0); \
    t1_ = __builtin_amdgcn_mfma_f32_16x16x32_bf16(ar[MI][1], bb[1][1], t1_, 0, 0, 0); \
    acc[(MH)*4 + (MI)][(NB) + 1] = t1_; }

#define SCHEDB __builtin_amdgcn_sched_barrier(0)
#define BSYNC { SCHEDB; __builtin_amdgcn_s_barrier(); SCHEDB; }

    auto PRIO1 = [&]() { __builtin_amdgcn_s_setprio(1); };
    auto PRIO0 = [&]() { __builtin_amdgcn_s_setprio(0); };

    // ---- prologue: tile0 -> b0 (8 loads), B(t1) -> b1 (4); vm(4) retires tile0
    ST_A(0, 0, 0); ST_A(0, 1, 0); ST_B(0, 0, 0); ST_B(0, 1, 0);
    ST_B(1, 0, 1); ST_B(1, 1, 1);
    asm volatile("s_waitcnt vmcnt(4)" ::: "memory");
    BSYNC;
    RD_BLO(0); RD_A2(0, 0, 0); RD_A2(0, 0, 2);

    for (int i = 0; i < NIT; ++i) {
        const int t0 = 2 * i;
        const bool last = (i == NIT - 1);

        // P1: M = t0 mh0 x blo.  R = bhi(b0)
        ST_A(t0 + 1, 0, 1);
        BSYNC; PRIO1();
        RD_BHI(0);
        MQ1(0, blo, 0, 0); MQ1(1, blo, 0, 0); MQ1(2, blo, 0, 0); MQ1(3, blo, 0, 0);
        PRIO0();

        // P2: M = t0 mh0 x bhi.  R = ar mh1(b0)
        ST_A(t0 + 1, 1, 1);
        BSYNC; PRIO1();
        MQ1(0, bhi, 0, 2); MQ1(1, bhi, 0, 2); MQ1(2, bhi, 0, 2); MQ1(3, bhi, 0, 2);
        RD_A2(0, 1, 0); RD_A2(0, 1, 2);
        PRIO0();

        // P3: M = t0 mh1 x bhi.
        BSYNC; PRIO1();
        MQ1(0, bhi, 1, 2); MQ1(1, bhi, 1, 2); MQ1(2, bhi, 1, 2); MQ1(3, bhi, 1, 2);
        PRIO0();

        // P4: stage BOTH b0.B halves (t0+2) + vm(4) retiring SA(t0+1);
        //     M = t0 mh1 x blo;  R = blo(b1)+ar mh0(b1)
        if (!last) { ST_B(t0 + 2, 0, 0); ST_B(t0 + 2, 1, 0);
                     asm volatile("s_waitcnt vmcnt(4)" ::: "memory"); }
        else       { asm volatile("s_waitcnt vmcnt(0)" ::: "memory"); }
        BSYNC; PRIO1();
        MQ1(0, blo, 1, 0); MQ1(1, blo, 1, 0); MQ1(2, blo, 1, 0); MQ1(3, blo, 1, 0);
        RD_BLO(1); RD_A2(1, 0, 0); RD_A2(1, 0, 2);
        PRIO0();

        // P5: M = t1 mh0 x blo.  R = bhi(b1)
        if (!last) ST_A(t0 + 2, 0, 0);
        BSYNC; PRIO1();
        RD_BHI(1);
        MQ1(0, blo, 0, 0); MQ1(1, blo, 0, 0); MQ1(2, blo, 0, 0); MQ1(3, blo, 0, 0);
        PRIO0();

        // P6: M = t1 mh0 x bhi.  R = ar mh1(b1)
        if (!last) ST_A(t0 + 2, 1, 0);
        BSYNC; PRIO1();
        MQ1(0, bhi, 0, 2); MQ1(1, bhi, 0, 2); MQ1(2, bhi, 0, 2); MQ1(3, bhi, 0, 2);
        RD_A2(1, 1, 0); RD_A2(1, 1, 2);
        PRIO0();

        // P7: M = t1 mh1 x bhi.
        BSYNC; PRIO1();
        MQ1(0, bhi, 1, 2); MQ1(1, bhi, 1, 2); MQ1(2, bhi, 1, 2); MQ1(3, bhi, 1, 2);
        PRIO0();

        // P8: stage BOTH b1.B halves (t0+3) + vm(4) retiring tile t0+2;
        //     M = t1 mh1 x blo;  R = next-iter blo(b0)+ar mh0(b0)
        if (!last) { ST_B(t0 + 3, 0, 1); ST_B(t0 + 3, 1, 1);
                     asm volatile("s_waitcnt vmcnt(4)" ::: "memory"); }
        BSYNC; PRIO1();
        MQ1(0, blo, 1, 0); MQ1(1, blo, 1, 0); MQ1(2, blo, 1, 0); MQ1(3, blo, 1, 0);
        if (!last) { RD_BLO(0); RD_A2(0, 0, 0); RD_A2(0, 0, 2); }
        PRIO0();
    }

    // ==================== epilogues ====================
    char* tw = lds + w * 16384;
    if constexpr (MODE == 2) {
        // masked exp transform (bf16-rounded into acc) + row partial sums
        const int q = lane >> 4, t = lane & 15;
        const bool diag = (bm == bn_s);
#pragma unroll
        for (int mi = 0; mi < 8; ++mi)
#pragma unroll
            for (int ni = 0; ni < 4; ++ni)
#pragma unroll
                for (int j = 0; j < 4; ++j) {
                    float e = __expf(acc[mi][ni][j] * scale);
                    if (diag) {
                        const int rl = wm * 128 + mi * 16 + q * 4 + j;
                        const int cl = wn * 64 + t + ni * 16;
                        if (cl > rl) e = 0.f;
                    }
                    e = __bfloat162float(__float2bfloat16(e));
                    acc[mi][ni][j] = e;
                }
        float* part = (float*)C1 + ((((long)zidx * 8 + bm) * 32) + bn_s * 4 + wn) * 256;
#pragma unroll
        for (int mi = 0; mi < 8; ++mi) {
            float rs0 = acc[mi][0][0] + acc[mi][1][0] + acc[mi][2][0] + acc[mi][3][0];
            float rs1 = acc[mi][0][1] + acc[mi][1][1] + acc[mi][2][1] + acc[mi][3][1];
            float rs2 = acc[mi][0][2] + acc[mi][1][2] + acc[mi][2][2] + acc[mi][3][2];
            float rs3 = acc[mi][0][3] + acc[mi][1][3] + acc[mi][2][3] + acc[mi][3][3];
#pragma unroll
            for (int d = 1; d < 16; d <<= 1) {
                rs0 += __shfl_xor(rs0, d); rs1 += __shfl_xor(rs1, d);
                rs2 += __shfl_xor(rs2, d); rs3 += __shfl_xor(rs3, d);
            }
            if (t == mi) {
                float4 o; o.x = rs0; o.y = rs1; o.z = rs2; o.w = rs3;
                *(float4*)(part + wm * 128 + mi * 16 + q * 4) = o;
            }
        }
    }
    if (MODE == 1 && seg == 1) {
        // V'T per batch via per-wave LDS transpose; 16B/lane column stores.
#pragma unroll
        for (int ni = 0; ni < 4; ++ni) {
            const int cl = ni * 16 + (lane & 15);
            const int sw = 8 * (cl & 7);
#pragma unroll
            for (int mi = 0; mi < 8; ++mi) {
                const int rlb = mi * 16 + ((lane >> 4) << 2);
                u16x4 o;
                o[0] = f2b(acc[mi][ni][0]); o[1] = f2b(acc[mi][ni][1]);
                o[2] = f2b(acc[mi][ni][2]); o[3] = f2b(acc[mi][ni][3]);
                *(u16x4*)(tw + cl * 256 + 2 * (rlb ^ sw)) = o;
            }
        }
        asm volatile("s_waitcnt lgkmcnt(0)" ::: "memory");
        __builtin_amdgcn_sched_barrier(0);
        const int m0 = rowA0 + wm * 128;
        const int z2 = m0 >> 11, mr = m0 & 2047;
        bf16* CT = (bf16*)C + (long)z2 * 2097152 + (long)(ccol0 + wn * 64 + lane) * 2048 + mr;
        const char* tr = tw + lane * 256;
        const int sw2 = lane & 7;
#pragma unroll
        for (int rb = 0; rb < 16; ++rb) {
            u16x8 v = *(const u16x8*)(tr + 16 * (rb ^ sw2));
            *(u16x8*)(CT + 8 * rb) = v;
        }
    } else {
        // bf16 row-retile: full 16B/lane row-segment stores
        const float sc2 = (MODE == 2) ? 1.0f : scale;
        const int q = lane >> 4, t = lane & 15;
        const int c0 = ccol0 + wn * 64 + t;
#pragma unroll
        for (int mi = 0; mi < 8; ++mi) {
            char* tm = tw + mi * 2048;
#pragma unroll
            for (int ni = 0; ni < 4; ++ni) {
                const float bv = bias ? bias[c0 + ni * 16] : 0.0f;
                const int cb = (t + 16 * ni) * 2;
#pragma unroll
                for (int j = 0; j < 4; ++j) {
                    const int rl = q * 4 + j;
                    *(bf16*)(tm + rl * 128 + (cb ^ ((rl & 7) << 4))) =
                        __float2bfloat16(acc[mi][ni][j] * sc2 + bv);
                }
            }
        }
        asm volatile("s_waitcnt lgkmcnt(0)" ::: "memory");
        __builtin_amdgcn_sched_barrier(0);
        const int rr2 = lane >> 2, chb = (lane & 3) * 2;
        const int gr0 = rowA0 + wm * 128;
        bf16* Cb = (bf16*)C;
        const int gcb = ccol0 + wn * 64;
#pragma unroll
        for (int mi = 0; mi < 8; ++mi) {
            const char* tm = tw + mi * 2048;
            const long gr = gr0 + mi * 16 + rr2;
#pragma unroll
            for (int k = 0; k < 2; ++k) {
                const int chunk = chb + k;
                u16x8 v = *(const u16x8*)(tm + rr2 * 128 + ((chunk << 4) ^ ((rr2 & 7) << 4)));
                *(u16x8*)(Cb + gr * (long)ldc + gcb + chunk * 8) = v;
            }
        }
    }
#undef RAF
#undef RBF
#undef RD_A2
#undef RD_BLO
#undef RD_BHI
#undef MQ1
#undef LA
#undef LB
}

// ============ balanced causal PV: out = (P' @ V'^T)/rowsum + bias ============
__global__ __launch_bounds__(512, 2) void pv_bal(
    const bf16* __restrict__ P, const bf16* __restrict__ VT,
    const float* __restrict__ part, float* __restrict__ out,
    const float* __restrict__ bias)
{
    __shared__ __align__(16) char lds[99328];  // 3 x 32KB bufs + 1KB inv
    float* invl = (float*)(lds + 98304);

    const int nwg = gridDim.x;
    const int bid = blockIdx.x;
    const int s = (bid & 7) * (nwg >> 3) + (bid >> 3);
    const int z = s >> 6, r = s & 63;
    const int pr = r >> 3, bn = r & 7;
    const int bmA = pr, bmB = 15 - pr;

    const bf16* Pz = P + (long)z * 2048 * 2048;
    const bf16* Vz = VT + (long)z * 1024 * 2048;

    const int tid = threadIdx.x;
    const int lane = tid & 63;
    const int w = tid >> 6;
    const int wm = w >> 2, wn = w & 3;
    const int rr = tid >> 3;
    const int lch = (tid & 7) ^ (rr & 7);

    if (tid < 256) {
        const int half = tid >> 7, rloc = tid & 127;
        const int grow = (half ? bmB : bmA) * 128 + rloc;
        const int b256 = grow >> 8, rin = grow & 255;
        const float* pp = part + (((long)z * 8 + b256) * 32) * 256 + rin;
        const int n4 = 4 * (b256 + 1);
        float s0 = 0.f, s1 = 0.f, s2 = 0.f, s3 = 0.f;
        int b4 = 0;
        for (; b4 + 4 <= n4; b4 += 4) {
            s0 += pp[(long)b4 * 256];       s1 += pp[(long)(b4 + 1) * 256];
            s2 += pp[(long)(b4 + 2) * 256]; s3 += pp[(long)(b4 + 3) * 256];
        }
        for (; b4 < n4; ++b4) s0 += pp[(long)b4 * 256];
        invl[tid] = 1.0f / ((s0 + s1) + (s2 + s3));
    }

    const bf16* gBt = Vz + (long)(bn * 128 + rr) * 2048 + lch * 8;
    const bf16* gAtA = Pz + (long)(bmA * 128 + rr) * 2048 + lch * 8;
    const bf16* gAtB = Pz + (long)(bmB * 128 + rr) * 2048 + lch * 8;

    auto SG2 = [&](const bf16* g, char* dst) {
        __builtin_amdgcn_global_load_lds((const AS1 void*)g,
            (AS3 void*)(dst + tid * 16), 16, 0, 0);
        __builtin_amdgcn_global_load_lds((const AS1 void*)(g + (long)64 * 2048),
            (AS3 void*)(dst + 8192 + tid * 16), 16, 0, 0);
    };
    auto ST = [&](const bf16* gAt, int kt, int b) {
        SG2(gAt + (long)kt * 64, lds + b * 32768);
        SG2(gBt + (long)kt * 64, lds + b * 32768 + 16384);
    };

    const int abase0 = (wm * 64 + (lane & 15)) * 128;
    const int bbase0 = 16384 + (wn * 32 + (lane & 15)) * 128;
    const int cc0 = ((lane >> 4) << 4) ^ ((lane & 7) << 4);
    const int cc1 = cc0 ^ 64;

    f32x4 acc[4][2];
    bf16x8 ar[4][2], br[2][2];

    auto RDF = [&](int t) {
        const char* base = lds + (t % 3) * 32768;
#pragma unroll
        for (int mi = 0; mi < 4; ++mi) {
            ar[mi][0] = *(const bf16x8*)(base + abase0 + mi * 2048 + cc0);
            ar[mi][1] = *(const bf16x8*)(base + abase0 + mi * 2048 + cc1);
        }
#pragma unroll
        for (int ni = 0; ni < 2; ++ni) {
            br[ni][0] = *(const bf16x8*)(base + bbase0 + ni * 2048 + cc0);
            br[ni][1] = *(const bf16x8*)(base + bbase0 + ni * 2048 + cc1);
        }
    };
    auto MFMA16 = [&]() {
#pragma unroll
        for (int mi = 0; mi < 4; ++mi)
#pragma unroll
            for (int ni = 0; ni < 2; ++ni) {
                f32x4 t_ = acc[mi][ni];
                t_ = __builtin_amdgcn_mfma_f32_16x16x32_bf16(ar[mi][0], br[ni][0], t_, 0, 0, 0);
                t_ = __builtin_amdgcn_mfma_f32_16x16x32_bf16(ar[mi][1], br[ni][1], t_, 0, 0, 0);
                acc[mi][ni] = t_;
            }
    };
    auto ZERO = [&]() {
#pragma unroll
        for (int mi = 0; mi < 4; ++mi)
#pragma unroll
            for (int ni = 0; ni < 2; ++ni) acc[mi][ni] = f32x4{0.f, 0.f, 0.f, 0.f};
    };
    auto tile_pass = [&](const bf16* gAt, int KT) {
        RDF(0);
        for (int t = 0; t < KT; ++t) {
            if (t + 2 < KT) {
                ST(gAt, t + 2, (t + 2) % 3);
                asm volatile("s_waitcnt vmcnt(4)" ::: "memory");
            } else if (t + 1 < KT) {
                asm volatile("s_waitcnt vmcnt(0)" ::: "memory");
            }
            asm volatile("s_waitcnt lgkmcnt(0)" ::: "memory");
            __builtin_amdgcn_sched_barrier(0);
            __builtin_amdgcn_s_barrier();
            __builtin_amdgcn_sched_barrier(0);
            __builtin_amdgcn_s_setprio(1);
            MFMA16();
            if (t + 1 < KT) RDF(t + 1);
            __builtin_amdgcn_s_setprio(0);
        }
    };
    auto epi = [&](int bm, int invoff) {
        const int q = lane >> 4, t16 = lane & 15;
        const int c0 = bn * 128 + wn * 32 + t16;
        float* op = out + ((long)z * 2048 + (long)bm * 128) * 1024;
#pragma unroll
        for (int mi = 0; mi < 4; ++mi)
#pragma unroll
            for (int j = 0; j < 4; ++j) {
                const int rl = wm * 64 + mi * 16 + q * 4 + j;
                const float iv = invl[invoff + rl];
#pragma unroll
                for (int ni = 0; ni < 2; ++ni) {
                    const int c = c0 + ni * 16;
                    op[(long)rl * 1024 + c] = acc[mi][ni][j] * iv + bias[c];
                }
            }
    };

    const int KTA = 2 * (bmA + 1), KTB = 2 * (bmB + 1);

    ST(gAtA, 0, 0); ST(gAtA, 1, 1);
    asm volatile("s_waitcnt vmcnt(4)" ::: "memory");
    __builtin_amdgcn_s_barrier();
    __builtin_amdgcn_sched_barrier(0);
    ZERO();
    tile_pass(gAtA, KTA);

    ST(gAtB, 0, 0); ST(gAtB, 1, 1);
    epi(bmA, 0);
    asm volatile("s_waitcnt vmcnt(0)" ::: "memory");
    __builtin_amdgcn_s_barrier();
    __builtin_amdgcn_sched_barrier(0);
    ZERO();
    tile_pass(gAtB, KTB);
    epi(bmB, 128);
}

extern "C" void kernel_launch(void* const* d_in, const int* in_sizes, int n_in,
                              void* d_out, int out_size, void* d_ws, size_t ws_size,
                              hipStream_t stream) {
    const int B = 4, S = 2048, D = 1024;
    const long MD = (long)B * S * D;
    const float scale = 0.5f / 32.0f;       // TAU / sqrt(D)

    const float* node  = (const float*)d_in[0];
    const float* label = (const float*)d_in[1];
    const float* Wq = (const float*)d_in[2];
    const float* bq = (const float*)d_in[3];
    const float* Wk = (const float*)d_in[4];
    const float* bk = (const float*)d_in[5];
    const float* Wv = (const float*)d_in[6];
    const float* bv = (const float*)d_in[7];
    const float* Wp = (const float*)d_in[8];
    const float* bp = (const float*)d_in[9];
    float* out = (float*)d_out;

    char* ws = (char*)d_ws;
    bf16* nodeb  = (bf16*)(ws);
    bf16* VTb    = nodeb;                          // alias (node dead after KV)
    bf16* labelb = (bf16*)(ws + 16777216);
    bf16* Wqb = (bf16*)(ws + 33554432);
    bf16* Wkb = (bf16*)(ws + 35651584);            // Wk|Wv contiguous
    bf16* Wvb = (bf16*)(ws + 37748736);
    bf16* Wpb = (bf16*)(ws + 39845888);
    bf16* Qb  = (bf16*)(ws + 41943040);
    bf16* Kb  = (bf16*)(ws + 58720256);
    bf16* Vb  = (bf16*)(ws + 75497472);
    float* partial = (float*)(ws + 75497472);      // alias (V dead after QVWp)
    bf16* SP  = (bf16*)(ws + 92274688);
    if (ws_size < 125829120UL) return;

    cvt6<<<dim3(512, 6), 256, 0, stream>>>(
        node, label, Wq, Wk, Wv, Wp,
        (u16x8*)nodeb, (u16x8*)labelb, (u16x8*)Wqb, (u16x8*)Wkb, (u16x8*)Wvb, (u16x8*)Wpb,
        MD / 8, (long)D * D / 8);

    // K|V projections: 256 blocks; B = stacked Wk|Wv
    gemmX<bf16, 0><<<256, 512, 0, stream>>>(
        nodeb, nullptr, Wkb, nullptr, Kb, Vb, bk, bv,
        1.0f, D, D, D, D, 0, 0, 0);

    // Q | V' = V@Wp^T (transposed write): 128+128 = 256 blocks
    gemmX<bf16, 1><<<256, 512, 0, stream>>>(
        labelb, Vb, Wqb, Wpb, Qb, VTb, bq, nullptr,
        1.0f, D, D, D, D, 0, 0, 0);

    // causal P' = exp((Q @ K^T)*scale) masked + row partial sums -> partial
    gemmX<bf16, 2><<<144, 512, 0, stream>>>(
        Qb, nullptr, Kb, (bf16*)nullptr, SP, (bf16*)partial, nullptr, nullptr,
        scale, D, D, S, D, (long)S * D, (long)S * D, (long)S * S);

    // out = (P' @ V'^T) / rowsum + bp (fp32), balanced pair grid: 256 blocks
    pv_bal<<<256, 512, 0, stream>>>(SP, VTb, partial, out, bp);
}